// Round 7
// baseline (150.877 us; speedup 1.0000x reference)
//
#include <hip/hip_runtime.h>

#define BATCH   1024
#define GROUPS  512

// r5 structure (XCD-partitioned dispatch, 1 group x 256 batches per block,
// LDS-staged params, plain stores) with ONE isolated change: 16 lanes per
// (b,g) instead of 8, so each store instruction writes 4 complete, aligned
// 256 B output rows (full L2 lines) instead of 8 scattered 128 B half-rows.
// Theory: partial-line stores trigger L2 write-allocate RFO fetches (~134 MB
// hidden HBM reads interleaved into the write stream) = the gap between the
// ~21 us write floor and the observed ~61 us kernel.
//
// LDS layout is now LINEAR (padding dropped): with 16 lanes reading one
// contiguous 256 B row slice per group, a wave's ds_read_b128 covers
// 4 groups x 64 consecutive words = every bank exactly 8x regardless of the
// data-dependent row indices -> conflict-free by construction (the 2 lanes
// per bank-pair case is the free 2-way of m136).
//
// (Resubmission of r6 -- container infra failure, kernel re-audited clean:
// mid-loop refill reads xv[p] before overwriting it; half 1 consumes the
// refilled passes 8..15; store covers full 256 B rows.)
__global__ __launch_bounds__(256) void hoact_kernel(
    const float4* __restrict__ X4,   // [B*G]       (4 f32 -> one float4)
    const float4* __restrict__ P4,   // [G*256]     (16 rows x 16 float4)
    float4*       __restrict__ O4)   // [B*G*16]
{
    __shared__ float tbl[16 * 64];   // 4 KiB, linear == params layout

    const int xcd   = blockIdx.x & 7;
    const int idx   = blockIdx.x >> 3;       // 0..255
    const int g     = xcd * 64 + (idx & 63); // contiguous 64-group slice per XCD
    const int chunk = idx >> 6;              // 0..3
    const int b0    = chunk * 256;
    const int tid   = threadIdx.x;           // 0..255

    // ---- stage params[g] into LDS (linear); L2-hit for 3 of the 4 chunks ----
    {
        const float4 v = P4[g * 256 + tid];          // coalesced 4 KiB
        *(float4*)&tbl[tid << 2] = v;                // ds_write_b128, linear
    }

    const int bl = tid >> 4;                 // 0..15: batch lane
    const int c4 = tid & 15;                 // float4 column within D=64

    // ---- prefetch X for the first 8 passes ----
    float4 xv[8];
#pragma unroll
    for (int p = 0; p < 8; ++p)
        xv[p] = X4[(b0 + p * 16 + bl) * GROUPS + g];  // 16-lane broadcast

    __syncthreads();

    // ---- pass-invariant row 15 (e0 == 15 for every input) ----
    const float4 p0 = *(const float4*)&tbl[15 * 64 + (c4 << 2)];

#pragma unroll
    for (int half = 0; half < 2; ++half) {
#pragma unroll
        for (int p = 0; p < 8; ++p) {
            const int pass = half * 8 + p;
            const int b    = b0 + pass * 16 + bl;
            const float4 x = xv[p];

            // xv[p] consumed into x above -> safe to refill for next half now
            // (issues the load 8 passes ahead; no clobber)
            if (half == 0)
                xv[p] = X4[(b0 + (8 + p) * 16 + bl) * GROUPS + g];

            // pack 2-bit source index into mantissa LSBs (<=3 ULP, harmless);
            // sort via fmin/fmax network; ties -> zero gap coef.
            float v0 = __uint_as_float((__float_as_uint(x.x) & ~3u) | 0u);
            float v1 = __uint_as_float((__float_as_uint(x.y) & ~3u) | 1u);
            float v2 = __uint_as_float((__float_as_uint(x.z) & ~3u) | 2u);
            float v3 = __uint_as_float((__float_as_uint(x.w) & ~3u) | 3u);

#define CSWAP(a, b_)                                 \
            {                                        \
                const float lo = fminf((a), (b_));   \
                const float hi = fmaxf((a), (b_));   \
                (a) = lo; (b_) = hi;                 \
            }
            CSWAP(v0, v1);
            CSWAP(v2, v3);
            CSWAP(v0, v2);
            CSWAP(v1, v3);
            CSWAP(v1, v2);
#undef CSWAP

            const int i1 = __float_as_uint(v1) & 3;
            const int i2 = __float_as_uint(v2) & 3;
            const int i3 = __float_as_uint(v3) & 3;

            const float c0 = v0;
            const float c1 = v1 - v0;
            const float c2 = v2 - v1;
            const float c3 = v3 - v2;

            const int e3 = 1 << i3;
            const int e2 = e3 + (1 << i2);
            const int e1 = e2 + (1 << i1);
            // e0 == 15 always (hoisted above)

            const float4 p1 = *(const float4*)&tbl[(e1 << 6) + (c4 << 2)];
            const float4 p2 = *(const float4*)&tbl[(e2 << 6) + (c4 << 2)];
            const float4 p3 = *(const float4*)&tbl[(e3 << 6) + (c4 << 2)];

            float4 o;
            o.x = c0 * p0.x + c1 * p1.x + c2 * p2.x + c3 * p3.x;
            o.y = c0 * p0.y + c1 * p1.y + c2 * p2.y + c3 * p3.y;
            o.z = c0 * p0.z + c1 * p1.z + c2 * p2.z + c3 * p3.z;
            o.w = c0 * p0.w + c1 * p1.w + c2 * p2.w + c3 * p3.w;

            // 16 lanes -> one complete 256 B output row; wave inst = 4 full
            // aligned rows. Plain store (no nontemporal).
            O4[b * (GROUPS * 16) + g * 16 + c4] = o;
        }
    }
}

extern "C" void kernel_launch(void* const* d_in, const int* in_sizes, int n_in,
                              void* d_out, int out_size, void* d_ws, size_t ws_size,
                              hipStream_t stream) {
    const float4* X4 = (const float4*)d_in[0];   // X: [1024, 512, 4] fp32
    const float4* P4 = (const float4*)d_in[1];   // params: [512, 16, 64] fp32
    float4*       O4 = (float4*)d_out;           // out: [1024, 512, 64] fp32

    const int grid = 2048;                       // 8 XCD x 64 g x 4 b-chunks
    hipLaunchKernelGGL(hoact_kernel, dim3(grid), dim3(256), 0, stream,
                       X4, P4, O4);
}

// Round 8
// 146.966 us; speedup vs baseline: 1.0266x; 1.0266x over previous
//
#include <hip/hip_runtime.h>

#define BATCH   1024
#define GROUPS  512
#define OUT_DIM 64

// Row stride in LDS words: 64 data + 4 pad (272 B/row): 16 B alignment for
// ds_read_b128; each 8-lane bg-group reads 32 consecutive words = every bank
// exactly once -> conflict-free regardless of the data-dependent row.
#define ROW_WORDS 68

typedef float f32x4 __attribute__((ext_vector_type(4)));

// r5 (best: 144.3 us) with ONE controlled change: force full occupancy.
// __launch_bounds__(256, 8) = 8 waves/EU = 32 waves/CU, which caps the
// register allocator at 64 VGPR. To fit without spilling, the X prefetch
// shrinks from xv[8] (32 VGPR held across the loop) to xv[4] + mid-loop
// refill (r7-audited pattern: each iteration reads its slot into x BEFORE
// overwriting it with the pass+4 load; half 1 consumes the refilled values).
//
// Theory: four structurally different kernels (128B/256B/1KiB stores,
// gather-from-L2) all land at ~62-71 us kernel vs a ~23 us traffic floor --
// layout-insensitive constant => latency exposure from low occupancy
// (unbounded VGPR likely >64, halving waves/CU), not bandwidth.
__global__ __launch_bounds__(256, 8) void hoact_kernel(
    const float4* __restrict__ X4,   // [B*G]       (4 f32 -> one float4)
    const float4* __restrict__ P4,   // [G*256]     (16 rows x 16 float4)
    float4*       __restrict__ O4)   // [B*G*16]
{
    __shared__ float tbl[16 * ROW_WORDS];

    const int xcd   = blockIdx.x & 7;
    const int idx   = blockIdx.x >> 3;       // 0..255
    const int g     = xcd * 64 + (idx & 63); // contiguous 64-group slice per XCD
    const int chunk = idx >> 6;              // 0..3
    const int b0    = chunk * 256;
    const int tid   = threadIdx.x;           // 0..255

    // ---- stage params[g] into LDS (row-padded); 4 co-resident chunks of the
    //      same g make this an L2 hit for 3 of the 4 ----
    {
        const float4 v = P4[g * 256 + tid];          // coalesced 4 KiB
        const int row = tid >> 4, c4 = tid & 15;
        *(float4*)&tbl[row * ROW_WORDS + c4 * 4] = v;  // ds_write_b128
    }

    const int t       = tid & 7;             // float4 column within D=64
    const int bl_base = tid >> 3;            // 0..31

    // ---- prefetch X for passes 0..3 only (16 VGPR, refilled mid-loop) ----
    float4 xv[4];
#pragma unroll
    for (int p = 0; p < 4; ++p) {
        const int b = b0 + p * 32 + bl_base;
        xv[p] = X4[b * GROUPS + g];          // 8 lanes broadcast one address
    }

    __syncthreads();

    // ---- pass-invariant row 15 (e0 == 15 for every input) ----
    const f32x4 p0a = *(const f32x4*)&tbl[15 * ROW_WORDS + t * 4];
    const f32x4 p0b = *(const f32x4*)&tbl[15 * ROW_WORDS + (t + 8) * 4];

#pragma unroll
    for (int half = 0; half < 2; ++half) {
#pragma unroll
        for (int p = 0; p < 4; ++p) {
            const int pass = half * 4 + p;
            const int b    = b0 + pass * 32 + bl_base;
            const float4 x = xv[p];

            // xv[p] consumed into x above -> safe to refill 4 passes ahead
            if (half == 0)
                xv[p] = X4[(b0 + (4 + p) * 32 + bl_base) * GROUPS + g];

            // pack 2-bit source index into mantissa LSBs (<=3 ULP, harmless);
            // sort via fmin/fmax network; ties -> zero gap coef.
            float v0 = __uint_as_float((__float_as_uint(x.x) & ~3u) | 0u);
            float v1 = __uint_as_float((__float_as_uint(x.y) & ~3u) | 1u);
            float v2 = __uint_as_float((__float_as_uint(x.z) & ~3u) | 2u);
            float v3 = __uint_as_float((__float_as_uint(x.w) & ~3u) | 3u);

#define CSWAP(a, b_)                                 \
            {                                        \
                const float lo = fminf((a), (b_));   \
                const float hi = fmaxf((a), (b_));   \
                (a) = lo; (b_) = hi;                 \
            }
            CSWAP(v0, v1);
            CSWAP(v2, v3);
            CSWAP(v0, v2);
            CSWAP(v1, v3);
            CSWAP(v1, v2);
#undef CSWAP

            const int i1 = __float_as_uint(v1) & 3;
            const int i2 = __float_as_uint(v2) & 3;
            const int i3 = __float_as_uint(v3) & 3;

            const float c0 = v0;
            const float c1 = v1 - v0;
            const float c2 = v2 - v1;
            const float c3 = v3 - v2;

            const int e3 = 1 << i3;
            const int e2 = e3 + (1 << i2);
            const int e1 = e2 + (1 << i1);
            // e0 == 15 always (hoisted above)

            const f32x4 p1a = *(const f32x4*)&tbl[e1 * ROW_WORDS + t * 4];
            const f32x4 p1b = *(const f32x4*)&tbl[e1 * ROW_WORDS + (t + 8) * 4];
            const f32x4 p2a = *(const f32x4*)&tbl[e2 * ROW_WORDS + t * 4];
            const f32x4 p2b = *(const f32x4*)&tbl[e2 * ROW_WORDS + (t + 8) * 4];
            const f32x4 p3a = *(const f32x4*)&tbl[e3 * ROW_WORDS + t * 4];
            const f32x4 p3b = *(const f32x4*)&tbl[e3 * ROW_WORDS + (t + 8) * 4];

            float4 oa, ob;
            oa.x = c0 * p0a.x + c1 * p1a.x + c2 * p2a.x + c3 * p3a.x;
            oa.y = c0 * p0a.y + c1 * p1a.y + c2 * p2a.y + c3 * p3a.y;
            oa.z = c0 * p0a.z + c1 * p1a.z + c2 * p2a.z + c3 * p3a.z;
            oa.w = c0 * p0a.w + c1 * p1a.w + c2 * p2a.w + c3 * p3a.w;
            ob.x = c0 * p0b.x + c1 * p1b.x + c2 * p2b.x + c3 * p3b.x;
            ob.y = c0 * p0b.y + c1 * p1b.y + c2 * p2b.y + c3 * p3b.y;
            ob.z = c0 * p0b.z + c1 * p1b.z + c2 * p2b.z + c3 * p3b.z;
            ob.w = c0 * p0b.w + c1 * p1b.w + c2 * p2b.w + c3 * p3b.w;

            // out[b][g][:]: 8 lanes -> 128 B contiguous runs; plain stores
            const int o_idx = b * (GROUPS * 16) + g * 16 + t;
            O4[o_idx]     = oa;
            O4[o_idx + 8] = ob;
        }
    }
}

extern "C" void kernel_launch(void* const* d_in, const int* in_sizes, int n_in,
                              void* d_out, int out_size, void* d_ws, size_t ws_size,
                              hipStream_t stream) {
    const float4* X4 = (const float4*)d_in[0];   // X: [1024, 512, 4] fp32
    const float4* P4 = (const float4*)d_in[1];   // params: [512, 16, 64] fp32
    float4*       O4 = (float4*)d_out;           // out: [1024, 512, 64] fp32

    const int grid = 2048;                       // 8 XCD x 64 g x 4 b-chunks
    hipLaunchKernelGGL(hoact_kernel, dim3(grid), dim3(256), 0, stream,
                       X4, P4, O4);
}